// Round 9
// baseline (344.133 us; speedup 1.0000x reference)
//
#include <hip/hip_runtime.h>
#include <cstdint>
#include <cstddef>

#define NH 8
#define DH 64
#define DM 512
#define CTX 64
#define BB 2
#define QL 2048
#define TT (QL + CTX - 1)   // 2111
#define HDIM 512
#define KVN 1024
#define KD 512              // K for all GEMMs

typedef unsigned short u16;
typedef __attribute__((ext_vector_type(8))) short bf16x8;   // 8 bf16 = 4 VGPRs
typedef __attribute__((ext_vector_type(4))) float f32x4;

__device__ __forceinline__ u16 f2bf(float f) {      // RNE float->bf16
    uint32_t u = __float_as_uint(f);
    u += 0x7FFF + ((u >> 16) & 1);
    return (u16)(u >> 16);
}
__device__ __forceinline__ uint32_t packbf(float lo, float hi) { // 2xbf16 in u32
    return (uint32_t)f2bf(lo) | ((uint32_t)f2bf(hi) << 16);
}

#define GLLDS(g, l) __builtin_amdgcn_global_load_lds( \
    (const __attribute__((address_space(1))) void*)(g), \
    (__attribute__((address_space(3))) void*)(l), 16, 0, 0)

// ===========================================================================
// Launch A ("front"): weight transposes (producers) + mask + G1/G3 (consumers
// spin on per-64-col-slice ready counters; bounded spin -> cannot hang).
// bids: [0,128) Wkv -> slices 0..15 | [128,192) Wq -> slices 16..23
//       [192,256) Wr -> slices 24..31 | [256,320) Wo (no counter)
//       [320,448) pad-mask | [448,1248) G1 (792) + G3 (8).
// Consumer LDS 24KB -> 6 blocks/CU -> all 1248 co-resident; producers are
// dispatched first. Producers: stores -> threadfence -> sync -> atomicAdd.
// ===========================================================================
__global__ __launch_bounds__(256) void front_kernel(
    const float* __restrict__ x, const float* __restrict__ r,
    const float* __restrict__ Wkv, const float* __restrict__ Wq,
    const float* __restrict__ bq, const float* __restrict__ Wr,
    const float* __restrict__ Wo,
    u16* __restrict__ WkvqT, u16* __restrict__ WrT, u16* __restrict__ WoT,
    u16* __restrict__ kvb, u16* __restrict__ hqb, u16* __restrict__ hrb,
    float* __restrict__ maskv, int* __restrict__ ctrs)
{
    const int bid = blockIdx.x;
    const int tid = threadIdx.x;
    int* wctr = ctrs;            // [32] weight-slice ready counters

    if (bid < 320) {                             // ---- weight transposes ----
        __shared__ float tile[64][65];
        const float* W; u16* WT; int N; int tidx; int slice;
        if (bid < 128)      { W = Wkv; WT = WkvqT;                    N = 1024; tidx = bid;       slice = tidx % 16; }
        else if (bid < 192) { W = Wq;  WT = WkvqT + (size_t)1024*512; N = 512;  tidx = bid - 128; slice = 16 + tidx % 8; }
        else if (bid < 256) { W = Wr;  WT = WrT;                      N = 512;  tidx = bid - 192; slice = 24 + tidx % 8; }
        else                { W = Wo;  WT = WoT;                      N = 512;  tidx = bid - 256; slice = -1; }
        const int tpr = N / 64;
        const int kb = (tidx / tpr) * 64, nb = (tidx % tpr) * 64;
        const int c4 = (tid & 15) * 4;
        for (int kk = tid >> 4; kk < 64; kk += 16) {
            float4 v = *(const float4*)&W[(size_t)(kb + kk) * N + nb + c4];
            tile[kk][c4 + 0] = v.x; tile[kk][c4 + 1] = v.y;
            tile[kk][c4 + 2] = v.z; tile[kk][c4 + 3] = v.w;
        }
        __syncthreads();
        for (int nn = tid >> 4; nn < 64; nn += 16) {
            ushort4 o;
            o.x = f2bf(tile[c4 + 0][nn]); o.y = f2bf(tile[c4 + 1][nn]);
            o.z = f2bf(tile[c4 + 2][nn]); o.w = f2bf(tile[c4 + 3][nn]);
            *(ushort4*)&WT[(size_t)(nb + nn) * KD + kb + c4] = o;
        }
        if (slice >= 0) {
            __threadfence();                     // release stores
            __syncthreads();
            if (tid == 0) atomicAdd(&wctr[slice], 1);
        }
        return;
    }
    if (bid < 448) {                             // ---- pad mask ----
        __shared__ int anyflag;
        int idx = bid - 320;
        int t = idx >> 1, b = idx & 1;
        const float* row = x + (size_t)(b * TT + t) * DM;
        bool nz = (row[tid] != 0.f) || (row[tid + 256] != 0.f);
        if (tid == 0) anyflag = 0;
        __syncthreads();
        unsigned long long bal = __ballot(nz);
        if ((tid & 63) == 0 && bal) atomicOr(&anyflag, 1);
        __syncthreads();
        if (tid == 0) maskv[b * 64 + t] = anyflag ? 0.f : -1e30f;
        return;
    }

    // ---- G1/G3 consumer: 128(M)x64(N) tiles, A from fp32, B bf16 GLLDS ----
    __shared__ __align__(16) u16 As[2][128 * 32];   // 16 KB
    __shared__ __align__(16) u16 Bs[2][64 * 32];    //  8 KB

    const int gbid = bid - 448;
    const int lane = tid & 63;
    const int w    = tid >> 6;
    const int wm   = w * 32;

    const bool g3 = (gbid >= 792);
    const float* A; const u16* BT; int m0, n0, mrows, slice;
    if (g3) { A = r; BT = WrT;   m0 = 0;                  n0 = (gbid - 792) * 64; mrows = CTX;     slice = 24 + (n0 >> 6); }
    else    { A = x; BT = WkvqT; m0 = (gbid / 24) * 128;  n0 = (gbid % 24) * 64;  mrows = BB * TT; slice = gbid % 24; }

    // A staging: thread covers row=tid>>1, k-half=(tid&1)*16 (16 fp32)
    const int arow = tid >> 1;
    const int akh  = (tid & 1) * 16;
    int grow = m0 + arow; if (grow >= mrows) grow = 0;   // clamp (outputs guarded)
    const float* gA = A + (size_t)grow * KD + akh;

    const int bn0 = tid >> 2;
    const int bk0 = (tid & 3) * 8;
    const u16* gb0 = BT + (size_t)(n0 + bn0) * KD + bk0;

    float4 f0, f1, f2, f3;
#define ALOAD1(kt) do { \
    f0 = *(const float4*)(gA + (kt));      f1 = *(const float4*)(gA + (kt) + 4); \
    f2 = *(const float4*)(gA + (kt) + 8);  f3 = *(const float4*)(gA + (kt) + 12); \
} while (0)
#define AWRITE1(buf) do { \
    uint4 p0, p1; \
    p0.x = packbf(f0.x, f0.y); p0.y = packbf(f0.z, f0.w); \
    p0.z = packbf(f1.x, f1.y); p0.w = packbf(f1.z, f1.w); \
    p1.x = packbf(f2.x, f2.y); p1.y = packbf(f2.z, f2.w); \
    p1.z = packbf(f3.x, f3.y); p1.w = packbf(f3.z, f3.w); \
    *(uint4*)&As[buf][arow * 32 + akh]     = p0; \
    *(uint4*)&As[buf][arow * 32 + akh + 8] = p1; \
} while (0)
#define BSTAGE1(buf, kt) GLLDS(gb0 + (kt), &Bs[buf][(size_t)w * 512])

    // issue independent A loads, then wait for weight slice
    ALOAD1(0);
    if (tid == 0) {
        int it = 0;
        while (__hip_atomic_load(&wctr[slice], __ATOMIC_ACQUIRE,
                                 __HIP_MEMORY_SCOPE_AGENT) < 8 && it < 200000) {
            __builtin_amdgcn_s_sleep(16); ++it;
        }
    }
    __syncthreads();
    __threadfence();                 // acquire: invalidate stale L2 before B reads

    f32x4 acc[2][4];
#pragma unroll
    for (int i = 0; i < 2; i++)
#pragma unroll
        for (int j = 0; j < 4; j++)
            acc[i][j] = (f32x4){0.f, 0.f, 0.f, 0.f};

    AWRITE1(0);
    BSTAGE1(0, 0);
    __syncthreads();

    int cur = 0;
    const int fm = lane & 15;
    const int fk = (lane >> 4) * 8;
    for (int kt = 0; kt < KD; kt += 32) {
        const bool more = (kt + 32 < KD);
        if (more) { ALOAD1(kt + 32); BSTAGE1(cur ^ 1, kt + 32); }

        bf16x8 af[2], bfr[4];
#pragma unroll
        for (int i = 0; i < 2; i++)
            af[i] = *(const bf16x8*)&As[cur][(wm + i * 16 + fm) * 32 + fk];
#pragma unroll
        for (int j = 0; j < 4; j++)
            bfr[j] = *(const bf16x8*)&Bs[cur][(j * 16 + fm) * 32 + fk];
#pragma unroll
        for (int i = 0; i < 2; i++)
#pragma unroll
            for (int j = 0; j < 4; j++)
                acc[i][j] = __builtin_amdgcn_mfma_f32_16x16x32_bf16(af[i], bfr[j], acc[i][j], 0, 0, 0);

        if (more) AWRITE1(cur ^ 1);
        __syncthreads();
        cur ^= 1;
    }
#undef ALOAD1
#undef AWRITE1
#undef BSTAGE1

    const int fc = lane & 15;
    const int fr = (lane >> 4) * 4;
    if (!g3) {
        const bool iskv = (n0 < 1024);
#pragma unroll
        for (int i = 0; i < 2; i++)
#pragma unroll
            for (int rr = 0; rr < 4; rr++) {
                int row = m0 + wm + i * 16 + fr + rr;
                if (row < BB * TT) {
                    if (iskv) {
#pragma unroll
                        for (int j = 0; j < 4; j++) {
                            int col = n0 + j * 16 + fc;
                            kvb[(size_t)row * KVN + col] = f2bf(acc[i][j][rr]);
                        }
                    } else {
                        int bb2 = row / TT;
                        int t   = row - bb2 * TT;
                        if (t >= CTX - 1) {
                            size_t orow = (size_t)(bb2 * QL + t - (CTX - 1));
#pragma unroll
                            for (int j = 0; j < 4; j++) {
                                int col = n0 + j * 16 + fc - 1024;
                                hqb[orow * HDIM + col] = f2bf(acc[i][j][rr] + bq[col]);
                            }
                        }
                    }
                }
            }
    } else {
#pragma unroll
        for (int i = 0; i < 2; i++)
#pragma unroll
            for (int rr = 0; rr < 4; rr++) {
                int row = m0 + wm + i * 16 + fr + rr;
                if (row < CTX) {
#pragma unroll
                    for (int j = 0; j < 4; j++) {
                        int col = n0 + j * 16 + fc;
                        hrb[(size_t)row * HDIM + col] = f2bf(acc[i][j][rr]);
                    }
                }
            }
    }
}

// ===========================================================================
// Launch B: attention (R7-verified body) + per-block G2 slice.
// Every block: attn for (qt,h,b) -> attnb; fence; atomicAdd actr[b,qt];
// bounded-spin until ==8; fence; then G2 64x64: out[rows of (b,qt)][h*64..]
// = attnb[64x512] @ WoT[h*64..][512]  (bf16 GLLDS both operands, 2-phase).
// 512 blocks @ 37888 LDS -> 4/CU -> all co-resident; spin bounded -> no hang.
// ===========================================================================
__global__ __launch_bounds__(256) void attn_g2(
    const u16* __restrict__ kvb, const u16* __restrict__ hqb,
    const u16* __restrict__ hrb, const float* __restrict__ maskv,
    u16* __restrict__ attnb, const u16* __restrict__ WoT,
    float* __restrict__ out, int* __restrict__ ctrs)
{
    __shared__ __align__(16) char lds[37888];
    float* sprime = (float*)lds;                 // [4][16][80] (band RMW stride 81)
    u16*   vTs    = (u16*)lds;                   // [64][136] — aliases sprime
    u16*   wband  = (u16*)(lds + 20480);         // [64][136]
    int* actr = ctrs + 32;                       // [64] attn-arrival counters

    const int q0 = blockIdx.x * 64;
    const int h  = blockIdx.y;
    const int b  = blockIdx.z;
    const int tid  = threadIdx.x;
    const int lane = tid & 63;
    const int w    = tid >> 6;
    const int qb   = q0 + w * 16;

    // ---- issue V loads early: 8 ushort4/thread, in flight until vTs write ----
    const int vr0 = tid >> 4;
    const int vc4 = (tid & 15) * 4;
    ushort4 vreg[8];
#pragma unroll
    for (int i = 0; i < 8; i++) {
        int rr = vr0 + i * 16;
        if (rr < 127)
            vreg[i] = *(const ushort4*)&kvb[(size_t)(b * TT + q0 + rr) * KVN + HDIM + h * DH + vc4];
        else
            vreg[i] = (ushort4){0, 0, 0, 0};     // pad column t=127 stays zero
    }

    // zero W' band buffer (64*136 u16 = 4352 u32)
    {
        uint32_t* wz = (uint32_t*)wband;
#pragma unroll
        for (int i = 0; i < 17; i++) wz[tid + i * 256] = 0;
    }
    // raw barrier with lgkm-only drain: V loads (vmcnt) stay outstanding
    asm volatile("s_waitcnt lgkmcnt(0)" ::: "memory");
    __builtin_amdgcn_s_barrier();

    const int fm = lane & 15;
    const int fk = (lane >> 4) * 8;

    const u16* hqrow = hqb + (size_t)(b * QL + qb + fm) * HDIM + h * DH + fk;
    bf16x8 afr0 = *(const bf16x8*)(hqrow);
    bf16x8 afr1 = *(const bf16x8*)(hqrow + 32);

    // ---- QK': S'[16 x 80] ----
    {
        const u16* kbase = kvb + (size_t)(b * TT + qb + fm) * KVN + h * DH + fk;
#pragma unroll
        for (int nt = 0; nt < 5; nt++) {
            bf16x8 b0 = *(const bf16x8*)(kbase + (size_t)nt * 16 * KVN);
            bf16x8 b1 = *(const bf16x8*)(kbase + (size_t)nt * 16 * KVN + 32);
            f32x4 acc = (f32x4){0.f, 0.f, 0.f, 0.f};
            acc = __builtin_amdgcn_mfma_f32_16x16x32_bf16(afr0, b0, acc, 0, 0, 0);
            acc = __builtin_amdgcn_mfma_f32_16x16x32_bf16(afr1, b1, acc, 0, 0, 0);
            const int row = (lane >> 4) * 4;
#pragma unroll
            for (int r2 = 0; r2 < 4; r2++)
                sprime[w * 1280 + (row + r2) * 80 + nt * 16 + fm] = acc[r2];
        }
    }
    // ---- S2 folded into sprime: s[m][m+c] += S2[m][c] (stride-81 band) ----
    {
        const u16* hrbase = hrb + (size_t)fm * HDIM + h * DH + fk;
#pragma unroll
        for (int nc = 0; nc < 4; nc++) {
            bf16x8 b0 = *(const bf16x8*)(hrbase + (size_t)nc * 16 * HDIM);
            bf16x8 b1 = *(const bf16x8*)(hrbase + (size_t)nc * 16 * HDIM + 32);
            f32x4 acc = (f32x4){0.f, 0.f, 0.f, 0.f};
            acc = __builtin_amdgcn_mfma_f32_16x16x32_bf16(afr0, b0, acc, 0, 0, 0);
            acc = __builtin_amdgcn_mfma_f32_16x16x32_bf16(afr1, b1, acc, 0, 0, 0);
            const int row = (lane >> 4) * 4;
#pragma unroll
            for (int r2 = 0; r2 < 4; r2++)
                sprime[w * 1280 + (row + r2) * 81 + nc * 16 + fm] += acc[r2];
        }
    }

    // ---- wave-parallel softmax: 4 lanes per row ----
    {
        const int i  = lane >> 2;
        const int g  = lane & 3;
        const int qloc = w * 16 + i;
        const float* srow = &sprime[w * 1280 + i * 81 + g * 16];
        float sv[16];
#pragma unroll
        for (int j = 0; j < 16; j++) sv[j] = srow[j] * 0.125f;
        if (q0 == 0) {
#pragma unroll
            for (int j = 0; j < 16; j++) {
                int t = qloc + g * 16 + j;
                if (t < 63) sv[j] += maskv[b * 64 + t];
            }
        }
        float mx = sv[0];
#pragma unroll
        for (int j = 1; j < 16; j++) mx = fmaxf(mx, sv[j]);
        mx = fmaxf(mx, __shfl_xor(mx, 1, 64));
        mx = fmaxf(mx, __shfl_xor(mx, 2, 64));
        float sum = 0.f;
#pragma unroll
        for (int j = 0; j < 16; j++) { sv[j] = __expf(sv[j] - mx); sum += sv[j]; }
        sum += __shfl_xor(sum, 1, 64);
        sum += __shfl_xor(sum, 2, 64);
        float inv = 1.f / sum;
        u16* wrow = &wband[qloc * 136 + qloc + g * 16];
#pragma unroll
        for (int j = 0; j < 16; j++) wrow[j] = f2bf(sv[j] * inv);
    }
    __syncthreads();   // ALL waves done reading sprime; wband complete

    // ---- write V transposed into sprime's (now dead) space ----
#pragma unroll
    for (int i = 0; i < 8; i++) {
        int rr = vr0 + i * 16;
        vTs[(vc4 + 0) * 136 + rr] = vreg[i].x;
        vTs[(vc4 + 1) * 136 + rr] = vreg[i].y;
        vTs[(vc4 + 2) * 136 + rr] = vreg[i].z;
        vTs[(vc4 + 3) * 136 + rr] = vreg[i].w;
    }
    __syncthreads();   // vTs complete

    // ---- PV: O[16 x 64] per wave = W'[16 x 128] @ V[128 x 64] ----
    f32x4 oacc[4];
#pragma unroll
    for (int j = 0; j < 4; j++) oacc[j] = (f32x4){0.f, 0.f, 0.f, 0.f};
#pragma unroll
    for (int ks = 0; ks < 4; ks++) {
        bf16x8 wa = *(const bf16x8*)&wband[(w * 16 + fm) * 136 + ks * 32 + fk];
#pragma unroll
        for (int j = 0; j < 4; j++) {
            bf16x8 vb = *(const bf16x8*)&vTs[(j * 16 + fm) * 136 + ks * 32 + fk];
            oacc[j] = __builtin_amdgcn_mfma_f32_16x16x32_bf16(wa, vb, oacc[j], 0, 0, 0);
        }
    }
    {
        const int row = (lane >> 4) * 4;
#pragma unroll
        for (int j = 0; j < 4; j++)
#pragma unroll
            for (int r2 = 0; r2 < 4; r2++)
                attnb[(size_t)(b * QL + qb + row + r2) * HDIM + h * DH + j * 16 + fm] =
                    f2bf(oacc[j][r2]);
    }

    // ---- arrival + bounded spin until all 8 heads of (b,q0) are done ----
    __threadfence();                 // release our attnb stores
    __syncthreads();                 // also: all LDS reads done (reuse below)
    if (tid == 0) {
        atomicAdd(&actr[b * 32 + blockIdx.x], 1);
        int it = 0;
        while (__hip_atomic_load(&actr[b * 32 + blockIdx.x], __ATOMIC_ACQUIRE,
                                 __HIP_MEMORY_SCOPE_AGENT) < 8 && it < 200000) {
            __builtin_amdgcn_s_sleep(16); ++it;
        }
    }
    __syncthreads();
    __threadfence();                 // acquire before reading peers' attnb

    // ---- G2 slice: out[64 rows of (b,q0)][h*64 .. h*64+63] ----
    {
        u16 (*As2)[64 * 32] = (u16 (*)[64 * 32])lds;            // 2 x 4 KB
        u16 (*Bs2)[64 * 32] = (u16 (*)[64 * 32])(lds + 8192);   // 2 x 4 KB

        const int m0 = b * QL + q0;
        const int n0 = h * 64;
        const int wm2 = (w >> 1) * 32;
        const int wn2 = (w & 1) * 32;

        const int am0 = tid >> 2;
        const int ak0 = (tid & 3) * 8;
        const u16* ga0 = attnb + (size_t)(m0 + am0) * HDIM + ak0;
        const u16* gb0 = WoT   + (size_t)(n0 + am0) * KD + ak0;

        f32x4 acc2[2][2];
#pragma unroll
        for (int i = 0; i < 2; i++)
#pragma unroll
            for (int j = 0; j < 2; j++)
                acc2[i][j] = (f32x4){0.f, 0.f, 0.f, 0.f};

        GLLDS(ga0, &As2[0][(size_t)w * 512]);
        GLLDS(gb0, &Bs2[0][(size_t)w * 512]);
        __syncthreads();

        int cur2 = 0;
        for (int kt = 0; kt < KD; kt += 32) {
            if (kt + 32 < KD) {
                GLLDS(ga0 + kt + 32, &As2[cur2 ^ 1][(size_t)w * 512]);
                GLLDS(gb0 + kt + 32, &Bs2[cur2 ^ 1][(size_t)w * 512]);
            }
            bf16x8 af2[2], bf2[2];
#pragma unroll
            for (int i = 0; i < 2; i++)
                af2[i] = *(const bf16x8*)&As2[cur2][(wm2 + i * 16 + fm) * 32 + fk];
#pragma unroll
            for (int j = 0; j < 2; j++)
                bf2[j] = *(const bf16x8*)&Bs2[cur2][(wn2 + j * 16 + fm) * 32 + fk];
#pragma unroll
            for (int i = 0; i < 2; i++)
#pragma unroll
                for (int j = 0; j < 2; j++)
                    acc2[i][j] = __builtin_amdgcn_mfma_f32_16x16x32_bf16(af2[i], bf2[j], acc2[i][j], 0, 0, 0);
            __syncthreads();
            cur2 ^= 1;
        }

        const int fc = lane & 15;
        const int fr = (lane >> 4) * 4;
#pragma unroll
        for (int i = 0; i < 2; i++)
#pragma unroll
            for (int rr = 0; rr < 4; rr++) {
                int row = m0 + wm2 + i * 16 + fr + rr;
#pragma unroll
                for (int j = 0; j < 2; j++) {
                    int col = n0 + wn2 + j * 16 + fc;
                    out[(size_t)row * DM + col] = acc2[i][j][rr];
                }
            }
    }
}

// ---------------------------------------------------------------------------
extern "C" void kernel_launch(void* const* d_in, const int* in_sizes, int n_in,
                              void* d_out, int out_size, void* d_ws, size_t ws_size,
                              hipStream_t stream)
{
    const float* x   = (const float*)d_in[0];
    const float* r   = (const float*)d_in[1];
    const float* Wkv = (const float*)d_in[2];
    const float* Wq  = (const float*)d_in[3];
    const float* bq  = (const float*)d_in[4];
    const float* Wr  = (const float*)d_in[5];
    const float* Wo  = (const float*)d_in[6];
    float* out = (float*)d_out;

    char* p = (char*)d_ws;
    u16* WkvqT  = (u16*)p;  p += (size_t)1536 * 512 * 2;
    u16* WrT    = (u16*)p;  p += (size_t)512 * 512 * 2;
    u16* WoT    = (u16*)p;  p += (size_t)512 * 512 * 2;
    u16* kvb    = (u16*)p;  p += (size_t)4224 * 1024 * 2;
    u16* hqb    = (u16*)p;  p += (size_t)4096 * 512 * 2;
    u16* hrb    = (u16*)p;  p += (size_t)64 * 512 * 2;
    u16* attnb  = (u16*)p;  p += (size_t)4096 * 512 * 2;
    float* maskv = (float*)p; p += 128 * sizeof(float);
    int* ctrs   = (int*)p;   // [32] weight slices + [64] attn arrivals

    hipMemsetAsync(ctrs, 0, 96 * sizeof(int), stream);
    // Launch A: weights + mask + G1/G3 (spin on weight slices)
    hipLaunchKernelGGL(front_kernel, dim3(1248), dim3(256), 0, stream,
                       x, r, Wkv, Wq, bq, Wr, Wo,
                       WkvqT, WrT, WoT, kvb, hqb, hrb, maskv, ctrs);
    // Launch B: attention + per-block G2 slice (spin on head arrivals)
    hipLaunchKernelGGL(attn_g2, dim3(QL / 64, NH, BB), dim3(256), 0, stream,
                       kvb, hqb, hrb, maskv, attnb, WoT, out, ctrs);
}

// Round 10
// 122.817 us; speedup vs baseline: 2.8020x; 2.8020x over previous
//
#include <hip/hip_runtime.h>
#include <cstdint>
#include <cstddef>

#define NH 8
#define DH 64
#define DM 512
#define CTX 64
#define BB 2
#define QL 2048
#define TT (QL + CTX - 1)   // 2111
#define HDIM 512
#define KVN 1024
#define KD 512              // K for all GEMMs

typedef unsigned short u16;
typedef __attribute__((ext_vector_type(8))) short bf16x8;   // 8 bf16 = 4 VGPRs
typedef __attribute__((ext_vector_type(4))) float f32x4;

__device__ __forceinline__ u16 f2bf(float f) {      // RNE float->bf16
    uint32_t u = __float_as_uint(f);
    u += 0x7FFF + ((u >> 16) & 1);
    return (u16)(u >> 16);
}
__device__ __forceinline__ uint32_t packbf(float lo, float hi) { // 2xbf16 in u32
    return (uint32_t)f2bf(lo) | ((uint32_t)f2bf(hi) << 16);
}

#define GLLDS(g, l) __builtin_amdgcn_global_load_lds( \
    (const __attribute__((address_space(1))) void*)(g), \
    (__attribute__((address_space(3))) void*)(l), 16, 0, 0)

// ===========================================================================
// Launch 1: G1 (bid<792) + G3 (792<=bid<800) + mask (800<=bid<928).
// A reg-staged from fp32 (x or r) -> packbf -> LDS bf16 (R7-verified path).
// B staged per-K-step DIRECTLY from fp32 weights, COALESCED:
//   thread (kkp=tid>>4, nj=(tid&15)*4) loads float4 from rows kt+2kkp and
//   kt+2kkp+1 (threads 0-15 cover 64 contiguous cols of one row), packs
//   4 k-pairs, writes 4 u32 into Bs u32-layout [n][20] (row stride 40 u16;
//   writes 2-way banks = free; b128 frag reads 16B-aligned, ~2-way).
//   Numerical layout identical to R8's (verified); only the load mapping
//   changed (R8's was uncoalesced -> 2x kernel cost).
// 128(M)x64(N) tiles, 2-phase prefetch, one barrier per K-step.
// LDS: As 16KB + Bs 10KB = 26.6KB -> 6 blocks/CU.
// ===========================================================================
__global__ __launch_bounds__(256) void gemm_fused(
    const float* __restrict__ x, const float* __restrict__ Wkv,
    const float* __restrict__ Wq, const float* __restrict__ bq,
    const float* __restrict__ r, const float* __restrict__ Wr,
    u16* __restrict__ kvb, u16* __restrict__ hqb, u16* __restrict__ hrb,
    float* __restrict__ maskv)
{
    const int bid = blockIdx.x;
    const int tid = threadIdx.x;

    if (bid >= 800) {                           // ---- pad mask ----
        __shared__ int anyflag;
        int idx = bid - 800;
        int t = idx >> 1, b = idx & 1;
        const float* row = x + (size_t)(b * TT + t) * DM;
        bool nz = (row[tid] != 0.f) || (row[tid + 256] != 0.f);
        if (tid == 0) anyflag = 0;
        __syncthreads();
        unsigned long long bal = __ballot(nz);
        if ((tid & 63) == 0 && bal) atomicOr(&anyflag, 1);
        __syncthreads();
        if (tid == 0) maskv[b * 64 + t] = anyflag ? 0.f : -1e30f;
        return;
    }

    __shared__ __align__(16) u16 As[2][128 * 32];       // 16 KB
    __shared__ __align__(16) uint32_t BsU[2][64 * 20];  // 10 KB

    const int lane = tid & 63;
    const int w    = tid >> 6;
    const int wm   = w * 32;                        // wave owns 32 M-rows

    const bool g3 = (bid >= 792);
    const float* A; const float* Bw; int ldb, coln, m0, n0, mrows;
    if (g3) {
        A = r; m0 = 0; n0 = (bid - 792) * 64; mrows = CTX;
        Bw = Wr; ldb = 512; coln = n0;
    } else {
        A = x; m0 = (bid / 24) * 128; n0 = (bid % 24) * 64; mrows = BB * TT;
        if (n0 < 1024) { Bw = Wkv; ldb = 1024; coln = n0; }
        else           { Bw = Wq;  ldb = 512;  coln = n0 - 1024; }
    }

    // A staging: thread covers row=tid>>1, k-half=(tid&1)*16 (16 fp32)
    const int arow = tid >> 1;
    const int akh  = (tid & 1) * 16;
    int grow = m0 + arow; if (grow >= mrows) grow = 0;   // clamp (outputs guarded)
    const float* gA = A + (size_t)grow * KD + akh;

    // B staging: thread covers k-pair kkp (rows 2kkp,2kkp+1), 4 cols at nj
    const int kkp = tid >> 4;                  // 0..15
    const int nj  = (tid & 15) * 4;            // 0..60
    const float* gB0 = Bw + (size_t)(2 * kkp) * ldb + coln + nj;
    const float* gB1 = gB0 + ldb;

    float4 f0, f1, f2, f3, ba, bb;
#define ALOAD1(kt) do { \
    f0 = *(const float4*)(gA + (kt));      f1 = *(const float4*)(gA + (kt) + 4); \
    f2 = *(const float4*)(gA + (kt) + 8);  f3 = *(const float4*)(gA + (kt) + 12); \
} while (0)
#define AWRITE1(buf) do { \
    uint4 p0, p1; \
    p0.x = packbf(f0.x, f0.y); p0.y = packbf(f0.z, f0.w); \
    p0.z = packbf(f1.x, f1.y); p0.w = packbf(f1.z, f1.w); \
    p1.x = packbf(f2.x, f2.y); p1.y = packbf(f2.z, f2.w); \
    p1.z = packbf(f3.x, f3.y); p1.w = packbf(f3.z, f3.w); \
    *(uint4*)&As[buf][arow * 32 + akh]     = p0; \
    *(uint4*)&As[buf][arow * 32 + akh + 8] = p1; \
} while (0)
#define BLOAD1(kt) do { \
    ba = *(const float4*)(gB0 + (size_t)(kt) * ldb); \
    bb = *(const float4*)(gB1 + (size_t)(kt) * ldb); \
} while (0)
#define BWRITE1(buf) do { \
    BsU[buf][(nj + 0) * 20 + kkp] = packbf(ba.x, bb.x); \
    BsU[buf][(nj + 1) * 20 + kkp] = packbf(ba.y, bb.y); \
    BsU[buf][(nj + 2) * 20 + kkp] = packbf(ba.z, bb.z); \
    BsU[buf][(nj + 3) * 20 + kkp] = packbf(ba.w, bb.w); \
} while (0)

    f32x4 acc[2][4];
#pragma unroll
    for (int i = 0; i < 2; i++)
#pragma unroll
        for (int j = 0; j < 4; j++)
            acc[i][j] = (f32x4){0.f, 0.f, 0.f, 0.f};

    ALOAD1(0); BLOAD1(0);
    AWRITE1(0); BWRITE1(0);
    __syncthreads();

    int cur = 0;
    const int fm = lane & 15;
    const int fk = (lane >> 4) * 8;
    for (int kt = 0; kt < KD; kt += 32) {
        const bool more = (kt + 32 < KD);
        if (more) { ALOAD1(kt + 32); BLOAD1(kt + 32); }

        const u16* Bs16 = (const u16*)&BsU[cur][0];
        bf16x8 af[2], bfr[4];
#pragma unroll
        for (int i = 0; i < 2; i++)
            af[i] = *(const bf16x8*)&As[cur][(wm + i * 16 + fm) * 32 + fk];
#pragma unroll
        for (int j = 0; j < 4; j++)
            bfr[j] = *(const bf16x8*)&Bs16[(j * 16 + fm) * 40 + fk];
#pragma unroll
        for (int i = 0; i < 2; i++)
#pragma unroll
            for (int j = 0; j < 4; j++)
                acc[i][j] = __builtin_amdgcn_mfma_f32_16x16x32_bf16(af[i], bfr[j], acc[i][j], 0, 0, 0);

        if (more) { AWRITE1(cur ^ 1); BWRITE1(cur ^ 1); }
        __syncthreads();
        cur ^= 1;
    }
#undef ALOAD1
#undef AWRITE1
#undef BLOAD1
#undef BWRITE1

    const int fc = lane & 15;
    const int fr = (lane >> 4) * 4;
    if (!g3) {
        const bool iskv = (n0 < 1024);
#pragma unroll
        for (int i = 0; i < 2; i++)
#pragma unroll
            for (int rr = 0; rr < 4; rr++) {
                int row = m0 + wm + i * 16 + fr + rr;
                if (row < BB * TT) {
                    if (iskv) {
#pragma unroll
                        for (int j = 0; j < 4; j++) {
                            int col = n0 + j * 16 + fc;
                            kvb[(size_t)row * KVN + col] = f2bf(acc[i][j][rr]);
                        }
                    } else {
                        int bb2 = row / TT;
                        int t   = row - bb2 * TT;
                        if (t >= CTX - 1) {
                            size_t orow = (size_t)(bb2 * QL + t - (CTX - 1));
#pragma unroll
                            for (int j = 0; j < 4; j++) {
                                int col = n0 + j * 16 + fc - 1024;
                                hqb[orow * HDIM + col] = f2bf(acc[i][j][rr] + bq[col]);
                            }
                        }
                    }
                }
            }
    } else {
#pragma unroll
        for (int i = 0; i < 2; i++)
#pragma unroll
            for (int rr = 0; rr < 4; rr++) {
                int row = m0 + wm + i * 16 + fr + rr;
                if (row < CTX) {
#pragma unroll
                    for (int j = 0; j < 4; j++) {
                        int col = n0 + j * 16 + fc;
                        hrb[(size_t)row * HDIM + col] = f2bf(acc[i][j][rr]);
                    }
                }
            }
    }
}

// ===========================================================================
// Launch 2: MFMA sliding-window relative attention (R7-verified, unchanged).
// LDS: sprime 20480 (aliased by vTs) | wband 17408 = 37888 -> 4 blocks/CU.
// ===========================================================================
__global__ __launch_bounds__(256, 4) void attn_mfma(
    const u16* __restrict__ kvb, const u16* __restrict__ hqb,
    const u16* __restrict__ hrb, const float* __restrict__ maskv,
    u16* __restrict__ attnb)
{
    __shared__ __align__(16) char lds[37888];
    float* sprime = (float*)lds;                 // [4][16][80] (band RMW stride 81)
    u16*   vTs    = (u16*)lds;                   // [64][136] — aliases sprime
    u16*   wband  = (u16*)(lds + 20480);         // [64][136]

    const int q0 = blockIdx.x * 64;
    const int h  = blockIdx.y;
    const int b  = blockIdx.z;
    const int tid  = threadIdx.x;
    const int lane = tid & 63;
    const int w    = tid >> 6;
    const int qb   = q0 + w * 16;

    // ---- issue V loads early: 8 ushort4/thread, in flight until vTs write ----
    const int vr0 = tid >> 4;
    const int vc4 = (tid & 15) * 4;
    ushort4 vreg[8];
#pragma unroll
    for (int i = 0; i < 8; i++) {
        int rr = vr0 + i * 16;
        if (rr < 127)
            vreg[i] = *(const ushort4*)&kvb[(size_t)(b * TT + q0 + rr) * KVN + HDIM + h * DH + vc4];
        else
            vreg[i] = (ushort4){0, 0, 0, 0};     // pad column t=127 stays zero
    }

    // zero W' band buffer (64*136 u16 = 4352 u32)
    {
        uint32_t* wz = (uint32_t*)wband;
#pragma unroll
        for (int i = 0; i < 17; i++) wz[tid + i * 256] = 0;
    }
    // raw barrier with lgkm-only drain: V loads (vmcnt) stay outstanding
    asm volatile("s_waitcnt lgkmcnt(0)" ::: "memory");
    __builtin_amdgcn_s_barrier();

    const int fm = lane & 15;
    const int fk = (lane >> 4) * 8;

    const u16* hqrow = hqb + (size_t)(b * QL + qb + fm) * HDIM + h * DH + fk;
    bf16x8 afr0 = *(const bf16x8*)(hqrow);
    bf16x8 afr1 = *(const bf16x8*)(hqrow + 32);

    // ---- QK': S'[16 x 80] ----
    {
        const u16* kbase = kvb + (size_t)(b * TT + qb + fm) * KVN + h * DH + fk;
#pragma unroll
        for (int nt = 0; nt < 5; nt++) {
            bf16x8 b0 = *(const bf16x8*)(kbase + (size_t)nt * 16 * KVN);
            bf16x8 b1 = *(const bf16x8*)(kbase + (size_t)nt * 16 * KVN + 32);
            f32x4 acc = (f32x4){0.f, 0.f, 0.f, 0.f};
            acc = __builtin_amdgcn_mfma_f32_16x16x32_bf16(afr0, b0, acc, 0, 0, 0);
            acc = __builtin_amdgcn_mfma_f32_16x16x32_bf16(afr1, b1, acc, 0, 0, 0);
            const int row = (lane >> 4) * 4;
#pragma unroll
            for (int r2 = 0; r2 < 4; r2++)
                sprime[w * 1280 + (row + r2) * 80 + nt * 16 + fm] = acc[r2];
        }
    }
    // ---- S2 folded into sprime: s[m][m+c] += S2[m][c] (stride-81 band) ----
    {
        const u16* hrbase = hrb + (size_t)fm * HDIM + h * DH + fk;
#pragma unroll
        for (int nc = 0; nc < 4; nc++) {
            bf16x8 b0 = *(const bf16x8*)(hrbase + (size_t)nc * 16 * HDIM);
            bf16x8 b1 = *(const bf16x8*)(hrbase + (size_t)nc * 16 * HDIM + 32);
            f32x4 acc = (f32x4){0.f, 0.f, 0.f, 0.f};
            acc = __builtin_amdgcn_mfma_f32_16x16x32_bf16(afr0, b0, acc, 0, 0, 0);
            acc = __builtin_amdgcn_mfma_f32_16x16x32_bf16(afr1, b1, acc, 0, 0, 0);
            const int row = (lane >> 4) * 4;
#pragma unroll
            for (int r2 = 0; r2 < 4; r2++)
                sprime[w * 1280 + (row + r2) * 81 + nc * 16 + fm] += acc[r2];
        }
    }

    // ---- wave-parallel softmax: 4 lanes per row ----
    {
        const int i  = lane >> 2;
        const int g  = lane & 3;
        const int qloc = w * 16 + i;
        const float* srow = &sprime[w * 1280 + i * 81 + g * 16];
        float sv[16];
#pragma unroll
        for (int j = 0; j < 16; j++) sv[j] = srow[j] * 0.125f;
        if (q0 == 0) {
#pragma unroll
            for (int j = 0; j < 16; j++) {
                int t = qloc + g * 16 + j;
                if (t < 63) sv[j] += maskv[b * 64 + t];
            }
        }
        float mx = sv[0];
#pragma unroll
        for (int j = 1; j < 16; j++) mx = fmaxf(mx, sv[j]);
        mx = fmaxf(mx, __shfl_xor(mx, 1, 64));
        mx = fmaxf(mx, __shfl_xor(mx, 2, 64));
        float sum = 0.f;
#pragma unroll
        for (int j = 0; j < 16; j++) { sv[j] = __expf(sv[j] - mx); sum += sv[j]; }
        sum += __shfl_xor(sum, 1, 64);
        sum += __shfl_xor(sum, 2, 64);
        float inv = 1.f / sum;
        u16* wrow = &wband[qloc * 136 + qloc + g * 16];
#pragma unroll
        for (int j = 0; j < 16; j++) wrow[j] = f2bf(sv[j] * inv);
    }
    __syncthreads();   // ALL waves done reading sprime; wband complete

    // ---- write V transposed into sprime's (now dead) space ----
#pragma unroll
    for (int i = 0; i < 8; i++) {
        int rr = vr0 + i * 16;
        vTs[(vc4 + 0) * 136 + rr] = vreg[i].x;
        vTs[(vc4 + 1) * 136 + rr] = vreg[i].y;
        vTs[(vc4 + 2) * 136 + rr] = vreg[i].z;
        vTs[(vc4 + 3) * 136 + rr] = vreg[i].w;
    }
    __syncthreads();   // vTs complete

    // ---- PV: O[16 x 64] per wave = W'[16 x 128] @ V[128 x 64] ----
    f32x4 oacc[4];
#pragma unroll
    for (int j = 0; j < 4; j++) oacc[j] = (f32x4){0.f, 0.f, 0.f, 0.f};
#pragma unroll
    for (int ks = 0; ks < 4; ks++) {
        bf16x8 wa = *(const bf16x8*)&wband[(w * 16 + fm) * 136 + ks * 32 + fk];
#pragma unroll
        for (int j = 0; j < 4; j++) {
            bf16x8 vb = *(const bf16x8*)&vTs[(j * 16 + fm) * 136 + ks * 32 + fk];
            oacc[j] = __builtin_amdgcn_mfma_f32_16x16x32_bf16(wa, vb, oacc[j], 0, 0, 0);
        }
    }
    {
        const int row = (lane >> 4) * 4;
#pragma unroll
        for (int j = 0; j < 4; j++)
#pragma unroll
            for (int r2 = 0; r2 < 4; r2++)
                attnb[(size_t)(b * QL + qb + row + r2) * HDIM + h * DH + j * 16 + fm] =
                    f2bf(oacc[j][r2]);
    }
}

// ===========================================================================
// Launch 3: G2 out = attnb @ Wo, 64x64 tiles (512 blocks), fp32 C.
// A = attnb bf16 via GLLDS (unchanged); B staged inline from fp32 Wo with
// the same coalesced k-pair scheme as G1. LDS 18.4KB -> 8 blocks/CU.
// ===========================================================================
__global__ __launch_bounds__(256) void gemm_n64(
    const u16* __restrict__ A, const float* __restrict__ Wo,
    float* __restrict__ C)
{
    __shared__ __align__(16) u16 As[2][64 * 32];        // 8 KB
    __shared__ __align__(16) uint32_t BsU[2][64 * 20];  // 10 KB

    const int tid  = threadIdx.x;
    const int lane = tid & 63;
    const int w    = tid >> 6;
    const int wm   = (w >> 1) * 32;
    const int wn   = (w & 1) * 32;
    const int m0   = (blockIdx.x >> 3) * 64;
    const int n0   = (blockIdx.x & 7) * 64;

    const int am0 = tid >> 2;
    const int ak0 = (tid & 3) * 8;
    const u16* ga0 = A + (size_t)(m0 + am0) * KD + ak0;

    const int kkp = tid >> 4;
    const int nj  = (tid & 15) * 4;
    const float* gB0 = Wo + (size_t)(2 * kkp) * DM + n0 + nj;
    const float* gB1 = gB0 + DM;

    float4 ba, bb;
#define BLOAD2(kt) do { \
    ba = *(const float4*)(gB0 + (size_t)(kt) * DM); \
    bb = *(const float4*)(gB1 + (size_t)(kt) * DM); \
} while (0)
#define BWRITE2(buf) do { \
    BsU[buf][(nj + 0) * 20 + kkp] = packbf(ba.x, bb.x); \
    BsU[buf][(nj + 1) * 20 + kkp] = packbf(ba.y, bb.y); \
    BsU[buf][(nj + 2) * 20 + kkp] = packbf(ba.z, bb.z); \
    BsU[buf][(nj + 3) * 20 + kkp] = packbf(ba.w, bb.w); \
} while (0)

    f32x4 acc[2][2];
#pragma unroll
    for (int i = 0; i < 2; i++)
#pragma unroll
        for (int j = 0; j < 2; j++)
            acc[i][j] = (f32x4){0.f, 0.f, 0.f, 0.f};

    BLOAD2(0);
    GLLDS(ga0, &As[0][(size_t)w * 512]);
    BWRITE2(0);
    __syncthreads();

    int cur = 0;
    const int fm = lane & 15;
    const int fk = (lane >> 4) * 8;
    for (int kt = 0; kt < KD; kt += 32) {
        const bool more = (kt + 32 < KD);
        if (more) {
            GLLDS(ga0 + kt + 32, &As[cur ^ 1][(size_t)w * 512]);
            BLOAD2(kt + 32);
        }
        const u16* Bs16 = (const u16*)&BsU[cur][0];
        bf16x8 af2[2], bf2[2];
#pragma unroll
        for (int i = 0; i < 2; i++)
            af2[i] = *(const bf16x8*)&As[cur][(wm + i * 16 + fm) * 32 + fk];
#pragma unroll
        for (int j = 0; j < 2; j++)
            bf2[j] = *(const bf16x8*)&Bs16[(wn + j * 16 + fm) * 40 + fk];
#pragma unroll
        for (int i = 0; i < 2; i++)
#pragma unroll
            for (int j = 0; j < 2; j++)
                acc[i][j] = __builtin_amdgcn_mfma_f32_16x16x32_bf16(af2[i], bf2[j], acc[i][j], 0, 0, 0);

        if (more) BWRITE2(cur ^ 1);
        __syncthreads();
        cur ^= 1;
    }
#undef BLOAD2
#undef BWRITE2

    const int fc = lane & 15;
    const int fr = (lane >> 4) * 4;
#pragma unroll
    for (int i = 0; i < 2; i++)
#pragma unroll
        for (int rr = 0; rr < 4; rr++) {
            int row = m0 + wm + i * 16 + fr + rr;
#pragma unroll
            for (int j = 0; j < 2; j++) {
                int col = n0 + wn + j * 16 + fc;
                C[(size_t)row * DM + col] = acc[i][j][rr];
            }
        }
}

// ---------------------------------------------------------------------------
extern "C" void kernel_launch(void* const* d_in, const int* in_sizes, int n_in,
                              void* d_out, int out_size, void* d_ws, size_t ws_size,
                              hipStream_t stream)
{
    const float* x   = (const float*)d_in[0];
    const float* r   = (const float*)d_in[1];
    const float* Wkv = (const float*)d_in[2];
    const float* Wq  = (const float*)d_in[3];
    const float* bq  = (const float*)d_in[4];
    const float* Wr  = (const float*)d_in[5];
    const float* Wo  = (const float*)d_in[6];
    float* out = (float*)d_out;

    char* p = (char*)d_ws;
    u16* kvb    = (u16*)p;  p += (size_t)4224 * 1024 * 2;
    u16* hqb    = (u16*)p;  p += (size_t)4096 * 512 * 2;
    u16* hrb    = (u16*)p;  p += (size_t)64 * 512 * 2;
    u16* attnb  = (u16*)p;  p += (size_t)4096 * 512 * 2;
    float* maskv = (float*)p;

    // 1) G1 + G3 + mask (B converted inline from fp32 weights; no prep pass)
    hipLaunchKernelGGL(gemm_fused, dim3(928), dim3(256), 0, stream,
                       x, Wkv, Wq, bq, r, Wr, kvb, hqb, hrb, maskv);
    // 2) attention
    hipLaunchKernelGGL(attn_mfma, dim3(QL / 64, NH, BB), dim3(256), 0, stream,
                       kvb, hqb, hrb, maskv, attnb);
    // 3) G2: out = attnb @ Wo (B converted inline)
    hipLaunchKernelGGL(gemm_n64, dim3(512), dim3(256), 0, stream,
                       attnb, Wo, out);
}